// Round 8
// baseline (180.521 us; speedup 1.0000x reference)
//
#include <hip/hip_runtime.h>
#include <math.h>

#define B_TOT   1024
#define S_DIM   64
#define N_DIM   256
#define UNFOLDS 12
#define EPSF    1e-8f
#define L2E     1.4426950408889634f
#define KMAX    256
#define ECLAMP  1073741824.0f   // 2^30: sigmoid clamp error <= 2^-30, quad product <= 2^121

// Guaranteed-native transcendentals.
#if defined(__has_builtin)
#  if __has_builtin(__builtin_amdgcn_exp2f)
#    define FEXP2(x) __builtin_amdgcn_exp2f(x)
#  endif
#  if __has_builtin(__builtin_amdgcn_rcpf)
#    define FRCP(x) __builtin_amdgcn_rcpf(x)
#  endif
#endif
#ifndef FEXP2
__device__ __forceinline__ float __fexp2_asm(float x){ float r; asm("v_exp_f32 %0, %1" : "=v"(r) : "v"(x)); return r; }
#  define FEXP2(x) __fexp2_asm(x)
#endif
#ifndef FRCP
__device__ __forceinline__ float __frcp_asm(float x){ float r; asm("v_rcp_f32 %0, %1" : "=v"(r) : "v"(x)); return r; }
#  define FRCP(x) __frcp_asm(x)
#endif

__device__ __forceinline__ float softplus_f(float x) {
    return log1pf(expf(x));
}

// Montgomery batch-inversion quad: 4 sigmoids r=1/(1+e) share ONE v_rcp.
// r0 = a1*a2*a3/(a0*a1*a2*a3) = 1/a0 exactly (up to ~1ulp rounding).
#define QUAD_BODY(p0, p1, vA0, vB0, vA1, vB1, mA, dA, mB, dB)               \
    {                                                                       \
        float t0 = fmaf(p0.x, vA0, p0.y);                                   \
        float t1 = fmaf(p0.x, vB0, p0.y);                                   \
        float t2 = fmaf(p1.x, vA1, p1.y);                                   \
        float t3 = fmaf(p1.x, vB1, p1.y);                                   \
        float e0 = fminf(FEXP2(t0), ECLAMP);                                \
        float e1 = fminf(FEXP2(t1), ECLAMP);                                \
        float e2 = fminf(FEXP2(t2), ECLAMP);                                \
        float e3 = fminf(FEXP2(t3), ECLAMP);                                \
        float a0 = 1.0f + e0, a1 = 1.0f + e1;                               \
        float a2 = 1.0f + e2, a3 = 1.0f + e3;                               \
        float b01 = a0 * a1, b23 = a2 * a3;                                 \
        float ip  = FRCP(b01 * b23);                                        \
        float ip01 = b23 * ip, ip23 = b01 * ip;                             \
        float r0 = a1 * ip01, r1 = a0 * ip01;                               \
        float r2 = a3 * ip23, r3 = a2 * ip23;                               \
        mA = fmaf(p0.w, r0, mA); dA = fmaf(p0.z, r0, dA);                   \
        mB = fmaf(p0.w, r1, mB); dB = fmaf(p0.z, r1, dB);                   \
        mA = fmaf(p1.w, r2, mA); dA = fmaf(p1.z, r2, dA);                   \
        mB = fmaf(p1.w, r3, mB); dB = fmaf(p1.z, r3, dB);                   \
    }

// Sensory params {A,B,WE,WEr} (s-major, j-contiguous), per-j combine constants,
// and per-wave-group max reset. sigmoid(sigma*(v-mu)) = 1/(1+exp2(A*v+B)).
__global__ void ltc_precompute_s(const float* __restrict__ gleak, const float* __restrict__ vleak,
                                 const float* __restrict__ cm,
                                 const float* __restrict__ sw,    const float* __restrict__ ssig,
                                 const float* __restrict__ smu,   const float* __restrict__ serev,
                                 const float* __restrict__ smask,
                                 float4* __restrict__ s4, float4* __restrict__ pj,
                                 int* __restrict__ wmax)
{
    const int idx = blockIdx.x * blockDim.x + threadIdx.x;
    if (idx < S_DIM * N_DIM) {
        float we = softplus_f(sw[idx]) * smask[idx];
        float sg = ssig[idx];
        float4 o;
        o.x = -L2E * sg;
        o.y =  L2E * sg * smu[idx];
        o.z =  we;
        o.w =  we * serev[idx];
        s4[idx] = o;
    }
    if (idx < N_DIM) {
        float g = softplus_f(gleak[idx]);
        float4 o;
        o.x = softplus_f(cm[idx]) * (float)UNFOLDS;  // cm_t
        o.y = g;
        o.z = g * vleak[idx];
        o.w = 0.0f;
        pj[idx] = o;
    }
    if (idx < 4) wmax[idx] = 0;
}

// Fused precompute + parallel compaction. One block per column j; ballot
// prefix-scan compacts live rows. pc is k-major [k][j] float4 (coalesced);
// pidxK is k-major [k][j] u8 (coalesced 64B/wave index stream). Zero-pad to
// KMAX (padding contributes exactly 0). Per-64-column-group max -> wmax.
__global__ __launch_bounds__(256)
void ltc_compact(const float* __restrict__ w,    const float* __restrict__ sigma,
                 const float* __restrict__ mu,   const float* __restrict__ erev,
                 const float* __restrict__ mask,
                 float4* __restrict__ pc, unsigned char* __restrict__ pidxK,
                 int* __restrict__ wmax)
{
    const int j = blockIdx.x;
    const int i = threadIdx.x;
    const int idx = i * N_DIM + j;

    const float mk = mask[idx];
    const bool live = mk > 0.0f;
    float we = softplus_f(w[idx]) * mk;
    float sg = sigma[idx];
    float4 o;
    o.x = -L2E * sg;
    o.y =  L2E * sg * mu[idx];
    o.z =  we;
    o.w =  we * erev[idx];

    const int lane = i & 63, wv = i >> 6;
    const unsigned long long ball = __ballot(live);
    const int lpre = __popcll(ball & ((1ull << lane) - 1ull));
    __shared__ int wcnt[4];
    if (lane == 0) wcnt[wv] = __popcll(ball);
    __syncthreads();
    int base = 0;
    #pragma unroll
    for (int ww = 0; ww < 4; ++ww) base += (ww < wv) ? wcnt[ww] : 0;
    const int total = wcnt[0] + wcnt[1] + wcnt[2] + wcnt[3];

    if (live) {
        const int pos = base + lpre;
        pc[pos * N_DIM + j] = o;
        pidxK[pos * N_DIM + j] = (unsigned char)i;
    }
    for (int k = total + i; k < KMAX; k += 256) {   // zero-pad (exact zeros)
        pc[k * N_DIM + j] = make_float4(0.f, 0.f, 0.f, 0.f);
        pidxK[k * N_DIM + j] = 0;
    }
    if (i == 0) atomicMax(&wmax[j >> 6], total);
}

// 512 threads/block, 512 blocks (2 batches each) -> 2 staggered blocks/CU.
// j = tid&255, q = tid>>8 (0/1); q covers half the compacted k-range, with a
// per-wave uniform bound from wmax. v double-buffered in LDS (swap pointers,
// named only). Montgomery quad = (2 k's) x (2 batches) share one rcp.
__global__ __launch_bounds__(512, 4)
void ltc_main(const float* __restrict__ inputs, const float* __restrict__ state,
              const float4* __restrict__ pc, const unsigned char* __restrict__ pidxK,
              const int* __restrict__ wmax,
              const float4* __restrict__ s4, const float4* __restrict__ pj,
              float* __restrict__ out)
{
    __shared__ float  vbuf[2][2][N_DIM];   // [buf][batch][i]
    __shared__ float4 pS[2][N_DIM];        // partials [q][j] = {mA,dA,mB,dB}
    __shared__ float  in_lds[2][S_DIM];

    const int tid = threadIdx.x;
    const int j   = tid & (N_DIM - 1);
    const int q   = tid >> 8;
    const int b0  = blockIdx.x << 1;

    // init v (1024 floats... 512 here: 2 batches x 256), coalesced
    {
        const int b = tid >> 8, i = tid & (N_DIM - 1);
        vbuf[0][b][i] = state[(b0 + b) * N_DIM + i];
    }
    if (tid < 2 * S_DIM) in_lds[tid >> 6][tid & 63] = inputs[b0 * S_DIM + tid];

    const float4 c = pj[j];
    const float cmt = c.x, gl = c.y, glv = c.z;
    const float cg  = cmt + gl + EPSF;

    // per-wave uniform compacted bound (same for both q of a j-group)
    const int wl   = wmax[j >> 6];
    const int U2w  = (((wl + 7) & ~7) >> 1);   // per-q k-count, multiple of 4
    __syncthreads();

    // ---- sensory pass: q covers s in [32q, 32q+32), Montgomery quads ----
    float snA = 0.f, sdA = 0.f, snB = 0.f, sdB = 0.f;
    {
        const float4* __restrict__ sr = s4 + (q << 5) * N_DIM + j;
        const int sb = q << 5;
        #pragma unroll 4
        for (int s = 0; s < 32; s += 2) {
            const float4 p0 = sr[s * N_DIM];
            const float4 p1 = sr[(s + 1) * N_DIM];
            const float iA0 = in_lds[0][sb + s],     iB0 = in_lds[1][sb + s];
            const float iA1 = in_lds[0][sb + s + 1], iB1 = in_lds[1][sb + s + 1];
            QUAD_BODY(p0, p1, iA0, iB0, iA1, iB1, snA, sdA, snB, sdB)
        }
    }
    pS[q][j] = make_float4(snA, sdA, snB, sdB);
    __syncthreads();

    // redundant sensory reduce into registers (both q identical)
    float4 sen, sed;
    {
        const float4 a0 = pS[0][j], a1 = pS[1][j];
        sen = make_float4(a0.x + a1.x, a0.z + a1.z, 0.f, 0.f);  // {numA, numB}
        sed = make_float4(a0.y + a1.y, a0.w + a1.w, 0.f, 0.f);  // {denA, denB}
    }
    __syncthreads();   // pS reused below

    // ---- 12 ODE unfolds ----
    const float4*        __restrict__ pr0 = pc    + (q * U2w) * N_DIM + j;
    const unsigned char* __restrict__ pi0 = pidxK + (q * U2w) * N_DIM + j;

    float* va = &vbuf[0][0][0];   // current
    float* vb = &vbuf[1][0][0];   // next

    #pragma unroll 1
    for (int step = 0; step < UNFOLDS; ++step) {
        float mA = 0.f, dA = 0.f, mB = 0.f, dB = 0.f;

        #pragma unroll 2
        for (int t = 0; t < U2w; t += 2) {
            const float4 p0 = pr0[t * N_DIM];
            const float4 p1 = pr0[(t + 1) * N_DIM];
            const int i0 = (int)pi0[t * N_DIM];
            const int i1 = (int)pi0[(t + 1) * N_DIM];
            const float vA0 = va[i0], vB0 = va[N_DIM + i0];   // LDS gather b32
            const float vA1 = va[i1], vB1 = va[N_DIM + i1];   // (+1024B imm)
            QUAD_BODY(p0, p1, vA0, vB0, vA1, vB1, mA, dA, mB, dB)
        }

        const float voA = va[j], voB = va[N_DIM + j];  // va not written this step
        pS[q][j] = make_float4(mA, dA, mB, dB);
        __syncthreads();

        // redundant combine in both q (bitwise-identical results)
        const float4 a0 = pS[0][j], a1 = pS[1][j];
        const float tnA = sen.x + a0.x + a1.x;
        const float tdA = sed.x + a0.y + a1.y;
        const float tnB = sen.y + a0.z + a1.z;
        const float tdB = sed.y + a0.w + a1.w;
        vb[j]         = (fmaf(cmt, voA, glv) + tnA) * FRCP(cg + tdA);
        vb[N_DIM + j] = (fmaf(cmt, voB, glv) + tnB) * FRCP(cg + tdB);
        __syncthreads();

        float* tmp = va; va = vb; vb = tmp;   // named swap, no indexing
    }

    // writeback: q handles batch b0+q, coalesced over j
    out[(b0 + q) * N_DIM + j] = va[q * N_DIM + j];
}

extern "C" void kernel_launch(void* const* d_in, const int* in_sizes, int n_in,
                              void* d_out, int out_size, void* d_ws, size_t ws_size,
                              hipStream_t stream)
{
    const float* inputs = (const float*)d_in[0];
    const float* state  = (const float*)d_in[1];
    const float* gleak  = (const float*)d_in[2];
    const float* vleak  = (const float*)d_in[3];
    const float* cm     = (const float*)d_in[4];
    const float* w      = (const float*)d_in[5];
    const float* sigma  = (const float*)d_in[6];
    const float* mu     = (const float*)d_in[7];
    const float* erev   = (const float*)d_in[8];
    const float* sw     = (const float*)d_in[9];
    const float* ssig   = (const float*)d_in[10];
    const float* smu    = (const float*)d_in[11];
    const float* serev  = (const float*)d_in[12];
    const float* mask   = (const float*)d_in[13];
    const float* smask  = (const float*)d_in[14];

    float4* s4 = (float4*)d_ws;                        // [S*N]    = 256 KiB
    float4* pj = s4 + S_DIM * N_DIM;                   // [N]      = 4 KiB
    float4* pc = pj + N_DIM;                           // [KMAX*N] = 1 MiB
    unsigned char* pidxK = (unsigned char*)(pc + KMAX * N_DIM);  // [KMAX][N] = 64 KiB
    int* wmax = (int*)(pidxK + KMAX * N_DIM);          // [4]

    ltc_precompute_s<<<(S_DIM * N_DIM + 255) / 256, 256, 0, stream>>>(
        gleak, vleak, cm, sw, ssig, smu, serev, smask, s4, pj, wmax);

    ltc_compact<<<N_DIM, 256, 0, stream>>>(w, sigma, mu, erev, mask, pc, pidxK, wmax);

    ltc_main<<<B_TOT / 2, 512, 0, stream>>>(inputs, state, pc, pidxK, wmax,
                                            s4, pj, (float*)d_out);
}

// Round 10
// 158.100 us; speedup vs baseline: 1.1418x; 1.1418x over previous
//
#include <hip/hip_runtime.h>
#include <math.h>

#define B_TOT   1024
#define S_DIM   64
#define N_DIM   256
#define UNFOLDS 12
#define EPSF    1e-8f
#define L2E     1.4426950408889634f
#define KMAX    256
#define ECLAMP  1073741824.0f   // 2^30: clamp err <= 2^-30; quad product <= 2^121 (finite)

// Guaranteed-native transcendentals.
#if defined(__has_builtin)
#  if __has_builtin(__builtin_amdgcn_exp2f)
#    define FEXP2(x) __builtin_amdgcn_exp2f(x)
#  endif
#  if __has_builtin(__builtin_amdgcn_rcpf)
#    define FRCP(x) __builtin_amdgcn_rcpf(x)
#  endif
#endif
#ifndef FEXP2
__device__ __forceinline__ float __fexp2_asm(float x){ float r; asm("v_exp_f32 %0, %1" : "=v"(r) : "v"(x)); return r; }
#  define FEXP2(x) __fexp2_asm(x)
#endif
#ifndef FRCP
__device__ __forceinline__ float __frcp_asm(float x){ float r; asm("v_rcp_f32 %0, %1" : "=v"(r) : "v"(x)); return r; }
#  define FRCP(x) __frcp_asm(x)
#endif

__device__ __forceinline__ float softplus_f(float x) {
    return log1pf(expf(x));
}

// Montgomery batch-inversion quad: 4 sigmoids r_i = 1/(1+e_i) share ONE v_rcp.
// One param float4 p (same k), 4 v values (4 batches). Exact algebra (~1ulp).
// ALL macro locals underscore-prefixed: R9 failed because a caller accumulator
// named e0 collided with the macro-local e0 (denominators were never summed).
#define MQUAD(p, v0, v1, v2, v3, m0, d0, m1, d1, m2, d2, m3, d3)            \
    {                                                                       \
        float _t0 = fmaf(p.x, v0, p.y);                                     \
        float _t1 = fmaf(p.x, v1, p.y);                                     \
        float _t2 = fmaf(p.x, v2, p.y);                                     \
        float _t3 = fmaf(p.x, v3, p.y);                                     \
        float _e0 = fminf(FEXP2(_t0), ECLAMP);                              \
        float _e1 = fminf(FEXP2(_t1), ECLAMP);                              \
        float _e2 = fminf(FEXP2(_t2), ECLAMP);                              \
        float _e3 = fminf(FEXP2(_t3), ECLAMP);                              \
        float _a0 = 1.0f + _e0, _a1 = 1.0f + _e1;                           \
        float _a2 = 1.0f + _e2, _a3 = 1.0f + _e3;                           \
        float _b01 = _a0 * _a1, _b23 = _a2 * _a3;                           \
        float _ip   = FRCP(_b01 * _b23);                                    \
        float _ip01 = _b23 * _ip, _ip23 = _b01 * _ip;                       \
        float _r0 = _a1 * _ip01, _r1 = _a0 * _ip01;                         \
        float _r2 = _a3 * _ip23, _r3 = _a2 * _ip23;                         \
        m0 = fmaf(p.w, _r0, m0); d0 = fmaf(p.z, _r0, d0);                   \
        m1 = fmaf(p.w, _r1, m1); d1 = fmaf(p.z, _r1, d1);                   \
        m2 = fmaf(p.w, _r2, m2); d2 = fmaf(p.z, _r2, d2);                   \
        m3 = fmaf(p.w, _r3, m3); d3 = fmaf(p.z, _r3, d3);                   \
    }

// Sensory params {A,B,WE,WEr} (s-major, j-contiguous), per-j combine constants,
// and wmax reset. sigmoid(sigma*(v-mu)) = 1/(1+exp2(A*v+B)).
__global__ void ltc_precompute_s(const float* __restrict__ gleak, const float* __restrict__ vleak,
                                 const float* __restrict__ cm,
                                 const float* __restrict__ sw,    const float* __restrict__ ssig,
                                 const float* __restrict__ smu,   const float* __restrict__ serev,
                                 const float* __restrict__ smask,
                                 float4* __restrict__ s4, float4* __restrict__ pj,
                                 int* __restrict__ wmax)
{
    const int idx = blockIdx.x * blockDim.x + threadIdx.x;
    if (idx < S_DIM * N_DIM) {
        float we = softplus_f(sw[idx]) * smask[idx];
        float sg = ssig[idx];
        float4 o;
        o.x = -L2E * sg;
        o.y =  L2E * sg * smu[idx];
        o.z =  we;
        o.w =  we * serev[idx];
        s4[idx] = o;
    }
    if (idx < N_DIM) {
        float g = softplus_f(gleak[idx]);
        float4 o;
        o.x = softplus_f(cm[idx]) * (float)UNFOLDS;  // cm_t
        o.y = g;
        o.z = g * vleak[idx];
        o.w = 0.0f;
        pj[idx] = o;
    }
    if (idx < 4) wmax[idx] = 0;
}

// Fused precompute + parallel compaction. One block per column j; ballot
// prefix-scan compacts live rows. pc is k-major [k][j] float4 (coalesced);
// pofs is k-major [k][j] u16 holding PRE-SHIFTED byte offsets (i<<4) for the
// b128 LDS gather. Zero-pad to KMAX (padding contributes exactly 0).
// Per-64-column-group max live count -> wmax[j>>6].
__global__ __launch_bounds__(256)
void ltc_compact(const float* __restrict__ w,    const float* __restrict__ sigma,
                 const float* __restrict__ mu,   const float* __restrict__ erev,
                 const float* __restrict__ mask,
                 float4* __restrict__ pc, unsigned short* __restrict__ pofs,
                 int* __restrict__ wmax)
{
    const int j = blockIdx.x;
    const int i = threadIdx.x;
    const int idx = i * N_DIM + j;

    const float mk = mask[idx];
    const bool live = mk > 0.0f;
    float we = softplus_f(w[idx]) * mk;
    float sg = sigma[idx];
    float4 o;
    o.x = -L2E * sg;
    o.y =  L2E * sg * mu[idx];
    o.z =  we;
    o.w =  we * erev[idx];

    const int lane = i & 63, wv = i >> 6;
    const unsigned long long ball = __ballot(live);
    const int lpre = __popcll(ball & ((1ull << lane) - 1ull));
    __shared__ int wcnt[4];
    if (lane == 0) wcnt[wv] = __popcll(ball);
    __syncthreads();
    int base = 0;
    #pragma unroll
    for (int ww = 0; ww < 4; ++ww) base += (ww < wv) ? wcnt[ww] : 0;
    const int total = wcnt[0] + wcnt[1] + wcnt[2] + wcnt[3];

    if (live) {
        const int pos = base + lpre;
        pc[pos * N_DIM + j] = o;
        pofs[pos * N_DIM + j] = (unsigned short)(i << 4);
    }
    for (int k = total + i; k < KMAX; k += 256) {   // zero-pad (exact zeros)
        pc[k * N_DIM + j] = make_float4(0.f, 0.f, 0.f, 0.f);
        pofs[k * N_DIM + j] = 0;
    }
    if (i == 0) atomicMax(&wmax[j >> 6], total);
}

// 1024 threads/block, 256 blocks, 4 batches each. j = tid&255, q = tid>>8
// (0..3); q covers a contiguous quarter of the compacted k-range, bounded by
// the per-wave-group max (wave-uniform). Per quad: 1 coalesced float4 param
// load + 1 coalesced u16 offset load + 1 b128 LDS gather + Montgomery quad
// (1 rcp / 4 sigmoids). All locals named scalars/float4 (R3: no arrays).
__global__ __launch_bounds__(1024, 2)
void ltc_main(const float* __restrict__ inputs, const float* __restrict__ state,
              const float4* __restrict__ pc, const unsigned short* __restrict__ pofs,
              const int* __restrict__ wmax,
              const float4* __restrict__ s4, const float4* __restrict__ pj,
              float* __restrict__ out)
{
    __shared__ float4 v4[N_DIM];        // v[i], component = batch
    __shared__ float4 pnum[4][N_DIM];   // partials [q][j]
    __shared__ float4 pden[4][N_DIM];
    __shared__ float  in_lds[4][S_DIM];

    const int tid = threadIdx.x;
    const int j   = tid & (N_DIM - 1);
    const int q   = tid >> 8;
    const int b0  = blockIdx.x << 2;

    ((float*)v4)[(j << 2) + q] = state[(b0 + q) * N_DIM + j];
    if (tid < 4 * S_DIM) in_lds[tid >> 6][tid & 63] = inputs[b0 * S_DIM + tid];

    const float4 c = pj[j];
    const float cmt = c.x, gl = c.y, glv = c.z;
    const float cg  = cmt + gl + EPSF;

    // per-wave-group uniform quad count: pad group max to multiple of 32,
    // quarter it (multiple of 8 -> clean unroll)
    const int wl  = wmax[j >> 6];
    const int U4w = ((wl + 31) & ~31) >> 2;
    __syncthreads();

    // ---- sensory pass: q covers s in [16q, 16q+16), Montgomery quads ----
    float n0 = 0.f, n1 = 0.f, n2 = 0.f, n3 = 0.f;
    float d0 = 0.f, d1 = 0.f, d2 = 0.f, d3 = 0.f;
    {
        const float4* __restrict__ sr = s4 + (q << 4) * N_DIM + j;
        const int sb = q << 4;
        #pragma unroll 4
        for (int s = 0; s < 16; ++s) {
            const float4 p = sr[s * N_DIM];
            const float i0 = in_lds[0][sb + s];
            const float i1 = in_lds[1][sb + s];
            const float i2 = in_lds[2][sb + s];
            const float i3 = in_lds[3][sb + s];
            MQUAD(p, i0, i1, i2, i3, n0, d0, n1, d1, n2, d2, n3, d3)
        }
    }
    pnum[q][j] = make_float4(n0, n1, n2, n3);
    pden[q][j] = make_float4(d0, d1, d2, d3);
    __syncthreads();

    // redundant sensory reduce into registers (all q identical)
    float4 sn = make_float4(0.f, 0.f, 0.f, 0.f);
    float4 sd = make_float4(0.f, 0.f, 0.f, 0.f);
    #pragma unroll
    for (int qq = 0; qq < 4; ++qq) {
        const float4 a = pnum[qq][j], b = pden[qq][j];
        sn.x += a.x; sn.y += a.y; sn.z += a.z; sn.w += a.w;
        sd.x += b.x; sd.y += b.y; sd.z += b.z; sd.w += b.w;
    }
    __syncthreads();   // pnum/pden reused below

    // ---- 12 ODE unfolds over the compacted list ----
    const float4*         __restrict__ pr = pc   + (q * U4w) * N_DIM + j;
    const unsigned short* __restrict__ po = pofs + (q * U4w) * N_DIM + j;

    #pragma unroll 1
    for (int step = 0; step < UNFOLDS; ++step) {
        float m0 = 0.f, m1 = 0.f, m2 = 0.f, m3 = 0.f;
        float h0 = 0.f, h1 = 0.f, h2 = 0.f, h3 = 0.f;   // denominator accums

        #pragma unroll 8
        for (int t = 0; t < U4w; ++t) {
            const float4 p   = pr[t * N_DIM];          // coalesced dwordx4
            const int    off = (int)po[t * N_DIM];     // coalesced u16 (pre-shifted i<<4)
            const float4 vv  = *(const float4*)((const char*)v4 + off);  // b128 gather
            MQUAD(p, vv.x, vv.y, vv.z, vv.w, m0, h0, m1, h1, m2, h2, m3, h3)
        }

        const float4 vo = v4[j];   // read old v BEFORE the barrier
        pnum[q][j] = make_float4(m0, m1, m2, m3);
        pden[q][j] = make_float4(h0, h1, h2, h3);
        __syncthreads();

        // redundant combine in all q-groups (bitwise-identical results);
        // Montgomery for the 4 division denominators (all > cg > 0, bounded).
        float4 tn = sn, td = sd;
        #pragma unroll
        for (int qq = 0; qq < 4; ++qq) {
            const float4 a = pnum[qq][j], b = pden[qq][j];
            tn.x += a.x; tn.y += a.y; tn.z += a.z; tn.w += a.w;
            td.x += b.x; td.y += b.y; td.z += b.z; td.w += b.w;
        }
        const float g0 = cg + td.x, g1 = cg + td.y;
        const float g2 = cg + td.z, g3 = cg + td.w;
        const float b01 = g0 * g1, b23 = g2 * g3;
        const float ip   = FRCP(b01 * b23);
        const float ip01 = b23 * ip, ip23 = b01 * ip;
        float4 vn;
        vn.x = (fmaf(cmt, vo.x, glv) + tn.x) * (g1 * ip01);
        vn.y = (fmaf(cmt, vo.y, glv) + tn.y) * (g0 * ip01);
        vn.z = (fmaf(cmt, vo.z, glv) + tn.z) * (g3 * ip23);
        vn.w = (fmaf(cmt, vo.w, glv) + tn.w) * (g2 * ip23);
        v4[j] = vn;                // 4 writers, identical bits — benign
        __syncthreads();
    }

    out[(b0 + q) * N_DIM + j] = ((const float*)v4)[(j << 2) + q];
}

extern "C" void kernel_launch(void* const* d_in, const int* in_sizes, int n_in,
                              void* d_out, int out_size, void* d_ws, size_t ws_size,
                              hipStream_t stream)
{
    const float* inputs = (const float*)d_in[0];
    const float* state  = (const float*)d_in[1];
    const float* gleak  = (const float*)d_in[2];
    const float* vleak  = (const float*)d_in[3];
    const float* cm     = (const float*)d_in[4];
    const float* w      = (const float*)d_in[5];
    const float* sigma  = (const float*)d_in[6];
    const float* mu     = (const float*)d_in[7];
    const float* erev   = (const float*)d_in[8];
    const float* sw     = (const float*)d_in[9];
    const float* ssig   = (const float*)d_in[10];
    const float* smu    = (const float*)d_in[11];
    const float* serev  = (const float*)d_in[12];
    const float* mask   = (const float*)d_in[13];
    const float* smask  = (const float*)d_in[14];

    float4* s4 = (float4*)d_ws;                        // [S*N]    = 256 KiB
    float4* pj = s4 + S_DIM * N_DIM;                   // [N]      = 4 KiB
    float4* pc = pj + N_DIM;                           // [KMAX*N] = 1 MiB
    unsigned short* pofs = (unsigned short*)(pc + KMAX * N_DIM);  // [KMAX][N] = 128 KiB
    int* wmax = (int*)(pofs + KMAX * N_DIM);           // [4]

    ltc_precompute_s<<<(S_DIM * N_DIM + 255) / 256, 256, 0, stream>>>(
        gleak, vleak, cm, sw, ssig, smu, serev, smask, s4, pj, wmax);

    ltc_compact<<<N_DIM, 256, 0, stream>>>(w, sigma, mu, erev, mask, pc, pofs, wmax);

    ltc_main<<<B_TOT / 4, 1024, 0, stream>>>(inputs, state, pc, pofs, wmax,
                                             s4, pj, (float*)d_out);
}